// Round 19
// baseline (458.589 us; speedup 1.0000x reference)
//
#include <hip/hip_runtime.h>

#define D 512
#define NTAB 100000
#define CAP0   128     // layer-0 merged row capacity (λ≈40)
#define CAP_S1 48      // layer-1 s rows (λ≈8)
#define CAP_F1 96      // layer-1 f rows (λ≈32)

typedef __bf16 bf16x8 __attribute__((ext_vector_type(8)));
typedef float f32x4 __attribute__((ext_vector_type(4)));
typedef float f32x2 __attribute__((ext_vector_type(2)));

__device__ __forceinline__ unsigned f2bf(float f){
  union { float f; unsigned u; } v; v.f = f;
  unsigned r = v.u + 0x7fffu + ((v.u >> 16) & 1u);
  return r >> 16;
}
__device__ __forceinline__ float bf2f(unsigned h){
  union { unsigned u; float f; } v; v.u = h << 16; return v.f;
}
__device__ __forceinline__ uint2 enc_fp8x8(f32x4 v0, f32x4 v1){
  int lo = __builtin_amdgcn_cvt_pk_fp8_f32(v0[0], v0[1], 0, false);
  lo     = __builtin_amdgcn_cvt_pk_fp8_f32(v0[2], v0[3], lo, true);
  int hi = __builtin_amdgcn_cvt_pk_fp8_f32(v1[0], v1[1], 0, false);
  hi     = __builtin_amdgcn_cvt_pk_fp8_f32(v1[2], v1[3], hi, true);
  return make_uint2((unsigned)lo, (unsigned)hi);
}

#define PER8 (NTAB*D/8)            // 6,400,000 8-elem units per table

// ===== MegaA: fillB (1/6) || {x-hist0->Dq, hist0->H0q} (5/6) || weights tail =====
#define MA_NS   6400
#define MA_GRID (MA_NS*6 + 512)

__global__ __launch_bounds__(256) void k_megaA(
    const int* __restrict__ s0r, const int* __restrict__ s0c, const float* __restrict__ s0v, int nS0,
    const int* __restrict__ f0r, const int* __restrict__ f0c, const float* __restrict__ f0v, int nF0,
    const int* __restrict__ s1r, const int* __restrict__ s1c, const float* __restrict__ s1v, int nS1,
    const int* __restrict__ f1r, const int* __restrict__ f1c, const float* __restrict__ f1v, int nF1,
    const int* __restrict__ sid0, const int* __restrict__ fid0, const int* __restrict__ fid1,
    int* __restrict__ cnt0, int2* __restrict__ bce0,
    int* __restrict__ cnt_s1, int2* __restrict__ bce_s1,
    int* __restrict__ cnt_f1, int2* __restrict__ bce_f1,
    const float* __restrict__ x, const float* __restrict__ hist0,
    unsigned char* __restrict__ TD,
    const float* __restrict__ w0, const float* __restrict__ w1,
    unsigned short* __restrict__ w0b, unsigned short* __restrict__ w1b)
{
  int b = blockIdx.x, t = threadIdx.x;
  if (b < MA_NS*6){
    int sb = b / 6, r = b % 6;
    if (r == 0){
      int i = sb*256 + t;                       // [0, 1638400) exact
      if (i < nS0){
        int rr = s0r[i];
        int c  = sid0[s0c[i]];                  // row of Dq
        int p = atomicAdd(&cnt0[rr], 1);
        if (p < CAP0) bce0[(size_t)rr*CAP0 + p] = make_int2(c, __float_as_int(s0v[i]));
        return;
      }
      i -= nS0;
      if (i < nF0){
        int rr = f0r[i];
        int c  = NTAB + fid0[f0c[i]];           // row of H0q
        int p = atomicAdd(&cnt0[rr], 1);
        if (p < CAP0) bce0[(size_t)rr*CAP0 + p] = make_int2(c, __float_as_int(f0v[i]));
        return;
      }
      i -= nF0;
      if (i < nS1){
        int rr = s1r[i];
        int p = atomicAdd(&cnt_s1[rr], 1);
        if (p < CAP_S1) bce_s1[(size_t)rr*CAP_S1 + p] = make_int2(s1c[i], __float_as_int(s1v[i]));
        return;
      }
      i -= nS1;
      {
        int rr = f1r[i];
        int c  = fid1[f1c[i]];                  // row of H1b
        int p = atomicAdd(&cnt_f1[rr], 1);
        if (p < CAP_F1) bce_f1[(size_t)rr*CAP_F1 + p] = make_int2(c, __float_as_int(f1v[i]));
      }
      return;
    }
    {
      int ci = (sb*5 + (r-1))*256 + t;          // guard PER8
      if (ci >= PER8) return;
      const f32x4* px = (const f32x4*)(x     + (size_t)ci*8);
      const f32x4* ph = (const f32x4*)(hist0 + (size_t)ci*8);
      f32x4 x0 = px[0];
      f32x4 x1 = px[1];
      f32x4 h0 = ph[0];
      f32x4 h1 = ph[1];
      *(uint2*)(TD + (size_t)ci*8)                    = enc_fp8x8(x0 - h0, x1 - h1);
      *(uint2*)(TD + (size_t)NTAB*D + (size_t)ci*8)   = enc_fp8x8(h0, h1);
      return;
    }
  } else {
    int i = (b - MA_NS*6)*256 + t;              // [0, 131072), 4 elems/thread
    const float* src = (i < 65536) ? w0 : w1;
    unsigned short* dst = (i < 65536) ? w0b : w1b;
    int ii = (i < 65536) ? i : i - 65536;
    f32x4 v = *(const f32x4*)(src + (size_t)ii*4);
    ushort4 o;
    o.x = (unsigned short)f2bf(v[0]); o.y = (unsigned short)f2bf(v[1]);
    o.z = (unsigned short)f2bf(v[2]); o.w = (unsigned short)f2bf(v[3]);
    *(ushort4*)(dst + (size_t)ii*4) = o;
  }
}

// ================= SpMM helpers (capacity-bin CSR) =================
__device__ __forceinline__ void acc_bf16(float* a, uint4 p, float v){
  a[0] += v*bf2f(p.x & 0xffffu); a[1] += v*bf2f(p.x >> 16);
  a[2] += v*bf2f(p.y & 0xffffu); a[3] += v*bf2f(p.y >> 16);
  a[4] += v*bf2f(p.z & 0xffffu); a[5] += v*bf2f(p.z >> 16);
  a[6] += v*bf2f(p.w & 0xffffu); a[7] += v*bf2f(p.w >> 16);
}
__device__ __forceinline__ void acc_fp8(float* a, uint2 q, float v){
  f32x2 d0 = __builtin_amdgcn_cvt_pk_f32_fp8(q.x, false);
  f32x2 d1 = __builtin_amdgcn_cvt_pk_f32_fp8(q.x, true);
  f32x2 d2 = __builtin_amdgcn_cvt_pk_f32_fp8(q.y, false);
  f32x2 d3 = __builtin_amdgcn_cvt_pk_f32_fp8(q.y, true);
  a[0] += v*d0[0]; a[1] += v*d0[1]; a[2] += v*d1[0]; a[3] += v*d1[1];
  a[4] += v*d2[0]; a[5] += v*d2[1]; a[6] += v*d3[0]; a[7] += v*d3[1];
}

__device__ __forceinline__ void spmm_run_bf16(
    const int2* __restrict__ be, int je,
    const unsigned short* __restrict__ H, int lane, float* a)
{
  int j = 0;
  for (; j + 8 <= je; j += 8){
    int2 e[8]; uint4 p[8];
    #pragma unroll
    for (int u=0;u<8;u++) e[u] = be[j+u];
    #pragma unroll
    for (int u=0;u<8;u++) p[u] = *(const uint4*)(H + (size_t)e[u].x*D + lane*8);
    #pragma unroll
    for (int u=0;u<8;u++) acc_bf16(a, p[u], __int_as_float(e[u].y));
  }
  if (j + 4 <= je){
    int2 e[4]; uint4 p[4];
    #pragma unroll
    for (int u=0;u<4;u++) e[u] = be[j+u];
    #pragma unroll
    for (int u=0;u<4;u++) p[u] = *(const uint4*)(H + (size_t)e[u].x*D + lane*8);
    #pragma unroll
    for (int u=0;u<4;u++) acc_bf16(a, p[u], __int_as_float(e[u].y));
    j += 4;
  }
  for (; j < je; j++){
    int2 e = be[j];
    uint4 p = *(const uint4*)(H + (size_t)e.x*D + lane*8);
    acc_bf16(a, p, __int_as_float(e.y));
  }
}

__device__ __forceinline__ void spmm_run_q8(
    const int2* __restrict__ be, int je,
    const unsigned char* __restrict__ Q, int lane, float* a)
{
  int j = 0;
  for (; j + 8 <= je; j += 8){
    int2 e[8]; uint2 q[8];
    #pragma unroll
    for (int u=0;u<8;u++) e[u] = be[j+u];
    #pragma unroll
    for (int u=0;u<8;u++) q[u] = *(const uint2*)(Q + (size_t)e[u].x*D + lane*8);
    #pragma unroll
    for (int u=0;u<8;u++) acc_fp8(a, q[u], __int_as_float(e[u].y));
  }
  if (j + 4 <= je){
    int2 e[4]; uint2 q[4];
    #pragma unroll
    for (int u=0;u<4;u++) e[u] = be[j+u];
    #pragma unroll
    for (int u=0;u<4;u++) q[u] = *(const uint2*)(Q + (size_t)e[u].x*D + lane*8);
    #pragma unroll
    for (int u=0;u<4;u++) acc_fp8(a, q[u], __int_as_float(e[u].y));
    j += 4;
  }
  for (; j < je; j++){
    int2 e = be[j];
    uint2 q = *(const uint2*)(Q + (size_t)e.x*D + lane*8);
    acc_fp8(a, q, __int_as_float(e.y));
  }
}

__device__ __forceinline__ void store_row(unsigned short* out, int row, int lane, const float* a){
  uint4 o;
  o.x = f2bf(a[0]) | (f2bf(a[1]) << 16);
  o.y = f2bf(a[2]) | (f2bf(a[3]) << 16);
  o.z = f2bf(a[4]) | (f2bf(a[5]) << 16);
  o.w = f2bf(a[6]) | (f2bf(a[7]) << 16);
  *(uint4*)(out + (size_t)row*D + lane*8) = o;
}

// ===== SpMMX: spmm0 over [Dq|H0q] (5/7) || hist1->H1b bf16 (2/7) =====
#define SX_NS   1639
#define SX_GRID (SX_NS*7)
#define CONV_BLKS 3125             // 3125*256*8 = 6.4M units

__global__ __launch_bounds__(256) void k_spmmX(
    const int* __restrict__ cnt0, const int2* __restrict__ bce0,
    const unsigned char* __restrict__ TD,
    unsigned short* __restrict__ out, int nrows,
    const float* __restrict__ hist1, unsigned short* __restrict__ H1b)
{
  int b = blockIdx.x, t = threadIdx.x;
  int sb = b / 7, r = b % 7;
  if (r < 5){
    int wid = t >> 6, lane = t & 63;
    int row = (sb*5 + r)*4 + wid;
    if (row >= nrows) return;
    float a[8] = {0.f,0.f,0.f,0.f,0.f,0.f,0.f,0.f};
    int je = min(cnt0[row], CAP0);
    spmm_run_q8(bce0 + (size_t)row*CAP0, je, TD, lane, a);
    store_row(out, row, lane, a);
  } else {
    int cb = sb*2 + (r-5);
    if (cb >= CONV_BLKS) return;
    #pragma unroll
    for (int k=0; k<8; k++){
      int ci = cb*256 + t + k*(CONV_BLKS*256);
      const f32x4* p = (const f32x4*)(hist1 + (size_t)ci*8);
      f32x4 v0 = p[0];
      f32x4 v1 = p[1];
      uint4 o;
      o.x = f2bf(v0[0]) | (f2bf(v0[1])<<16);
      o.y = f2bf(v0[2]) | (f2bf(v0[3])<<16);
      o.z = f2bf(v1[0]) | (f2bf(v1[1])<<16);
      o.w = f2bf(v1[2]) | (f2bf(v1[3])<<16);
      *(uint4*)(H1b + (size_t)ci*8) = o;
    }
  }
}

__global__ __launch_bounds__(256) void k_spmm_acc(
    const int* __restrict__ cnt, const int2* __restrict__ bce, const unsigned short* __restrict__ H,
    unsigned short* __restrict__ out, int nrows)
{
  int wid = threadIdx.x >> 6, lane = threadIdx.x & 63;
  int row = blockIdx.x*4 + wid;
  if (row >= nrows) return;
  float a[8];
  uint4 p = *(const uint4*)(out + (size_t)row*D + lane*8);
  a[0]=bf2f(p.x&0xffffu); a[1]=bf2f(p.x>>16); a[2]=bf2f(p.y&0xffffu); a[3]=bf2f(p.y>>16);
  a[4]=bf2f(p.z&0xffffu); a[5]=bf2f(p.z>>16); a[6]=bf2f(p.w&0xffffu); a[7]=bf2f(p.w>>16);
  int je = min(cnt[row], CAP_S1);
  spmm_run_bf16(bce + (size_t)row*CAP_S1, je, H, lane, a);
  store_row(out, row, lane, a);
}

// ================= GEMM =================
__device__ __forceinline__ void gload16(const unsigned short* g, unsigned short* l){
  __builtin_amdgcn_global_load_lds(
      (const __attribute__((address_space(1))) unsigned int*)(const void*)g,
      (__attribute__((address_space(3))) unsigned int*)(void*)l,
      16, 0, 0);
}

template<bool OUT_BF16>
__device__ __forceinline__ void gemm_block(
    const unsigned short* __restrict__ A,
    const unsigned short* __restrict__ B,
    const float* __restrict__ bias,
    void* __restrict__ Cv,
    int gemm_bid, unsigned short* Al, unsigned short* Bl)
{
  int bx = gemm_bid & 3, by = gemm_bid >> 2;
  int m0 = by << 7, n0 = bx << 7;
  int t = threadIdx.x, wave = t >> 6, lane = t & 63;
  int wr = wave >> 1, wc = wave & 1;
  f32x4 acc[4][4] = {};
  int flat = t << 3;
  int r0 = flat >> 5, cc = flat & 31;
  const unsigned short* pa = A + (size_t)(m0 + r0)*D + cc;
  const unsigned short* pb = B + (size_t)(n0 + r0)*D + cc;
  for (int k0 = 0; k0 < D; k0 += 32){
    gload16(pa + k0,                 &Al[flat]);
    gload16(pa + (size_t)64*D + k0,  &Al[flat + 2048]);
    gload16(pb + k0,                 &Bl[flat]);
    gload16(pb + (size_t)64*D + k0,  &Bl[flat + 2048]);
    __syncthreads();
    int arow = (wr << 6) | (lane & 15);
    int brow = (wc << 6) | (lane & 15);
    int kg   = (lane >> 4) << 3;
    bf16x8 af[4], bfr[4];
    #pragma unroll
    for (int mi=0; mi<4; mi++) af[mi]  = *(const bf16x8*)&Al[(arow + (mi<<4))*32 + kg];
    #pragma unroll
    for (int ni=0; ni<4; ni++) bfr[ni] = *(const bf16x8*)&Bl[(brow + (ni<<4))*32 + kg];
    #pragma unroll
    for (int mi=0; mi<4; mi++)
      #pragma unroll
      for (int ni=0; ni<4; ni++)
        acc[mi][ni] = __builtin_amdgcn_mfma_f32_16x16x32_bf16(af[mi], bfr[ni], acc[mi][ni], 0, 0, 0);
    __syncthreads();
  }
  int crow = m0 + (wr << 6) + ((lane >> 4) << 2);
  int ccol = n0 + (wc << 6) + (lane & 15);
  #pragma unroll
  for (int mi=0; mi<4; mi++){
    #pragma unroll
    for (int q=0; q<4; q++){
      int row = crow + (mi << 4) + q;
      #pragma unroll
      for (int ni=0; ni<4; ni++){
        float val = acc[mi][ni][q] + bias[ccol + (ni << 4)];
        if (OUT_BF16)
          ((unsigned short*)Cv)[(size_t)row*D + ccol + (ni << 4)] = (unsigned short)f2bf(val);
        else
          ((float*)Cv)[(size_t)row*D + ccol + (ni << 4)] = val;
      }
    }
  }
}

// MegaC: gemm0 (1/3) || spmm1 f-init over H1b bf16 (2/3)
__global__ __launch_bounds__(256) void k_megaC(
    const unsigned short* __restrict__ A, const unsigned short* __restrict__ B,
    const float* __restrict__ bias, unsigned short* __restrict__ y1,
    const int* __restrict__ cnt_f1, const int2* __restrict__ bce_f1,
    const unsigned short* __restrict__ H1b, unsigned short* __restrict__ out2, int n2rows)
{
  __shared__ unsigned short Al[128*32];
  __shared__ unsigned short Bl[128*32];
  int b = blockIdx.x, t = threadIdx.x;
  int sb = b / 3, r = b % 3;
  if (r == 0){
    gemm_block<true>(A, B, bias, (void*)y1, sb, Al, Bl);
  } else {
    int wid = t >> 6, lane = t & 63;
    int row = (sb*2 + (r-1))*4 + wid;
    if (row >= n2rows) return;
    float a[8] = {0.f,0.f,0.f,0.f,0.f,0.f,0.f,0.f};
    int je = min(cnt_f1[row], CAP_F1);
    spmm_run_bf16(bce_f1 + (size_t)row*CAP_F1, je, H1b, lane, a);
    store_row(out2, row, lane, a);
  }
}

template<bool OUT_BF16>
__global__ __launch_bounds__(256) void k_gemm_bias(
    const unsigned short* __restrict__ A,
    const unsigned short* __restrict__ B,
    const float* __restrict__ bias,
    void* __restrict__ Cv,
    int M)
{
  __shared__ unsigned short Al[128*32];
  __shared__ unsigned short Bl[128*32];
  gemm_block<OUT_BF16>(A, B, bias, Cv, blockIdx.x, Al, Bl);
}

// ================= LN + ReLU - bf16 H1b[sid1] =================
__global__ __launch_bounds__(256) void k_ln_relu_sub(
    const unsigned short* __restrict__ y, const float* __restrict__ gam, const float* __restrict__ bet,
    const unsigned short* __restrict__ H1b, const int* __restrict__ sid1,
    unsigned short* __restrict__ out)
{
  __shared__ float sh[8];
  int row = blockIdx.x, t = threadIdx.x;
  int c = t << 1;
  unsigned pv = *(const unsigned*)(y + (size_t)row*D + c);
  float vx = bf2f(pv & 0xffffu), vy = bf2f(pv >> 16);
  float s = vx + vy, ss = vx*vx + vy*vy;
  #pragma unroll
  for (int m=1; m<64; m<<=1){ s += __shfl_xor(s, m); ss += __shfl_xor(ss, m); }
  int wave = t >> 6, lane = t & 63;
  if (lane == 0){ sh[wave] = s; sh[4+wave] = ss; }
  __syncthreads();
  s  = sh[0]+sh[1]+sh[2]+sh[3];
  ss = sh[4]+sh[5]+sh[6]+sh[7];
  float mu  = s * (1.f/D);
  float var = ss * (1.f/D) - mu*mu;
  float rr  = rsqrtf(var + 1e-5f);
  int srow = sid1[row];
  unsigned hv = *(const unsigned*)(H1b + (size_t)srow*D + c);
  float o0 = fmaxf((vx - mu)*rr*gam[c]   + bet[c],   0.f) - bf2f(hv & 0xffffu);
  float o1 = fmaxf((vy - mu)*rr*gam[c+1] + bet[c+1], 0.f) - bf2f(hv >> 16);
  *(unsigned*)(out + (size_t)row*D + c) = f2bf(o0) | (f2bf(o1) << 16);
}

// ================= log_softmax =================
__global__ __launch_bounds__(256) void k_logsoftmax(const float* __restrict__ y, float* __restrict__ out){
  __shared__ float sh[8];
  int row = blockIdx.x, t = threadIdx.x;
  int c = t << 1;
  float2 v = *(const float2*)(y + (size_t)row*D + c);
  float m = fmaxf(v.x, v.y);
  #pragma unroll
  for (int k=1; k<64; k<<=1) m = fmaxf(m, __shfl_xor(m, k));
  int wave = t >> 6, lane = t & 63;
  if (lane == 0) sh[wave] = m;
  __syncthreads();
  m = fmaxf(fmaxf(sh[0], sh[1]), fmaxf(sh[2], sh[3]));
  __syncthreads();
  float e = expf(v.x - m) + expf(v.y - m);
  #pragma unroll
  for (int k=1; k<64; k<<=1) e += __shfl_xor(e, k);
  if (lane == 0) sh[4+wave] = e;
  __syncthreads();
  e = sh[4]+sh[5]+sh[6]+sh[7];
  float lse = m + logf(e);
  float2 o; o.x = v.x - lse; o.y = v.y - lse;
  *(float2*)(out + (size_t)row*D + c) = o;
}

extern "C" void kernel_launch(void* const* d_in, const int* in_sizes, int n_in,
                              void* d_out, int out_size, void* d_ws, size_t ws_size,
                              hipStream_t stream)
{
  const float* x     = (const float*)d_in[0];
  const float* hist0 = (const float*)d_in[1];
  const float* hist1 = (const float*)d_in[2];
  const float* w0    = (const float*)d_in[3];
  const float* b0    = (const float*)d_in[4];
  const float* g0    = (const float*)d_in[5];
  const float* beta0 = (const float*)d_in[6];
  const float* w1    = (const float*)d_in[7];
  const float* b1    = (const float*)d_in[8];
  const float* s0v   = (const float*)d_in[9];
  const float* s1v   = (const float*)d_in[10];
  const float* f0v   = (const float*)d_in[11];
  const float* f1v   = (const float*)d_in[12];
  const int* sid0    = (const int*)d_in[13];
  const int* sid1    = (const int*)d_in[14];
  const int* fid0    = (const int*)d_in[16];
  const int* fid1    = (const int*)d_in[17];
  const int* s0r     = (const int*)d_in[18];
  const int* s0c     = (const int*)d_in[19];
  const int* s1r     = (const int*)d_in[20];
  const int* s1c     = (const int*)d_in[21];
  const int* f0r     = (const int*)d_in[22];
  const int* f0c     = (const int*)d_in[23];
  const int* f1r     = (const int*)d_in[24];
  const int* f1c     = (const int*)d_in[25];

  const int N1 = 32768, N2 = 8192;
  const int Es0 = 262144, Es1 = 65536, Ef0 = 1048576, Ef1 = 262144;

  char* ws = (char*)d_ws;
  size_t off = 0;
  auto alloc = [&](size_t bytes)->char*{
    char* p = ws + off; off += (bytes + 255) & ~(size_t)255; return p;
  };
  char* TD_raw = alloc((size_t)2*NTAB*D);         // 102.4MB fp8 [Dq|H0q]; dead after spmmX
  unsigned short* H1b = (unsigned short*)alloc((size_t)NTAB*D*2);  // 102.4MB bf16 hist1
  unsigned short* h1   = (unsigned short*)alloc((size_t)N1*D*2);
  unsigned short* out1 = (unsigned short*)alloc((size_t)N1*D*2);
  unsigned short* w0b  = (unsigned short*)alloc((size_t)D*D*2);
  unsigned short* w1b  = (unsigned short*)alloc((size_t)D*D*2);
  int* cnt0   = (int*)alloc((size_t)N1*4);
  int* cnt_s1 = (int*)alloc((size_t)N2*4);
  int* cnt_f1 = (int*)alloc((size_t)N2*4);
  int2* bce0   = (int2*)alloc((size_t)N1*CAP0*8);     // 33.6MB
  int2* bce_s1 = (int2*)alloc((size_t)N2*CAP_S1*8);   // 3.1MB
  int2* bce_f1 = (int2*)alloc((size_t)N2*CAP_F1*8);   // 6.3MB

  unsigned char*  TD   = (unsigned char*)TD_raw;
  unsigned short* y1   = (unsigned short*)TD_raw;                      // @0 after spmmX
  float*          y2   = (float*)(TD_raw + ((size_t)34<<20));
  unsigned short* out2 = (unsigned short*)(TD_raw + ((size_t)52<<20));
  float*          outp = (float*)d_out;

  hipMemsetAsync(cnt0, 0, (size_t)(N1 + 2*N2)*4, stream);
  // MegaA: fills (capacity bins) || (x-hist0)->Dq + hist0->H0q || weights->bf16
  k_megaA<<<MA_GRID, 256, 0, stream>>>(
      s0r, s0c, s0v, Es0, f0r, f0c, f0v, Ef0,
      s1r, s1c, s1v, Es1, f1r, f1c, f1v, Ef1,
      sid0, fid0, fid1,
      cnt0, bce0, cnt_s1, bce_s1, cnt_f1, bce_f1,
      x, hist0, TD, w0, w1, w0b, w1b);
  // SpMMX: layer-0 merged fp8 SpMM || hist1->H1b
  k_spmmX<<<SX_GRID, 256, 0, stream>>>(cnt0, bce0, TD, out1, N1, hist1, H1b);
  // MegaC: gemm0 (out1@w0 -> y1 bf16) || spmm1 f-init (H1b -> out2)
  k_megaC<<<1024*3, 256, 0, stream>>>(out1, w0b, b0, y1, cnt_f1, bce_f1, H1b, out2, N2);
  // LN + ReLU - bf16 H1b[sid1] -> h1
  k_ln_relu_sub<<<N1, 256, 0, stream>>>(y1, g0, beta0, H1b, sid1, h1);
  // layer-1 s-phase accumulate
  k_spmm_acc<<<N2/4, 256, 0, stream>>>(cnt_s1, bce_s1, h1, out2, N2);
  // dense + log-softmax
  k_gemm_bias<false><<<(N2/128)*4, 256, 0, stream>>>(out2, w1b, b1, (void*)y2, N2);
  k_logsoftmax<<<N2, 256, 0, stream>>>(y2, outp);
}

// Round 20
// 448.529 us; speedup vs baseline: 1.0224x; 1.0224x over previous
//
#include <hip/hip_runtime.h>

#define D 512
#define NTAB 100000
#define CAP0   128     // layer-0 merged row capacity (λ≈40)
#define CAP_S1 48      // layer-1 s rows (λ≈8)
#define CAP_F1 96      // layer-1 f rows (λ≈32)

typedef __bf16 bf16x8 __attribute__((ext_vector_type(8)));
typedef float f32x4 __attribute__((ext_vector_type(4)));
typedef float f32x2 __attribute__((ext_vector_type(2)));

__device__ __forceinline__ unsigned f2bf(float f){
  union { float f; unsigned u; } v; v.f = f;
  unsigned r = v.u + 0x7fffu + ((v.u >> 16) & 1u);
  return r >> 16;
}
__device__ __forceinline__ float bf2f(unsigned h){
  union { unsigned u; float f; } v; v.u = h << 16; return v.f;
}
__device__ __forceinline__ uint2 enc_fp8x8(f32x4 v0, f32x4 v1){
  int lo = __builtin_amdgcn_cvt_pk_fp8_f32(v0[0], v0[1], 0, false);
  lo     = __builtin_amdgcn_cvt_pk_fp8_f32(v0[2], v0[3], lo, true);
  int hi = __builtin_amdgcn_cvt_pk_fp8_f32(v1[0], v1[1], 0, false);
  hi     = __builtin_amdgcn_cvt_pk_fp8_f32(v1[2], v1[3], hi, true);
  return make_uint2((unsigned)lo, (unsigned)hi);
}

#define PER8 (NTAB*D/8)            // 6,400,000 8-elem units per table

// ===== MegaA: fillB (1/6) || {x-hist0->Dq, hist0->H0q} (5/6) || weights tail =====
#define MA_NS   6400
#define MA_GRID (MA_NS*6 + 512)

__global__ __launch_bounds__(256) void k_megaA(
    const int* __restrict__ s0r, const int* __restrict__ s0c, const float* __restrict__ s0v, int nS0,
    const int* __restrict__ f0r, const int* __restrict__ f0c, const float* __restrict__ f0v, int nF0,
    const int* __restrict__ s1r, const int* __restrict__ s1c, const float* __restrict__ s1v, int nS1,
    const int* __restrict__ f1r, const int* __restrict__ f1c, const float* __restrict__ f1v, int nF1,
    const int* __restrict__ sid0, const int* __restrict__ fid0, const int* __restrict__ fid1,
    int* __restrict__ cnt0, int2* __restrict__ bce0,
    int* __restrict__ cnt_s1, int2* __restrict__ bce_s1,
    int* __restrict__ cnt_f1, int2* __restrict__ bce_f1,
    const float* __restrict__ x, const float* __restrict__ hist0,
    unsigned char* __restrict__ TD,
    const float* __restrict__ w0, const float* __restrict__ w1,
    unsigned short* __restrict__ w0b, unsigned short* __restrict__ w1b)
{
  int b = blockIdx.x, t = threadIdx.x;
  if (b < MA_NS*6){
    int sb = b / 6, r = b % 6;
    if (r == 0){
      int i = sb*256 + t;                       // [0, 1638400) exact
      if (i < nS0){
        int rr = s0r[i];
        int c  = sid0[s0c[i]];                  // row of Dq
        int p = atomicAdd(&cnt0[rr], 1);
        if (p < CAP0) bce0[(size_t)rr*CAP0 + p] = make_int2(c, __float_as_int(s0v[i]));
        return;
      }
      i -= nS0;
      if (i < nF0){
        int rr = f0r[i];
        int c  = NTAB + fid0[f0c[i]];           // row of H0q
        int p = atomicAdd(&cnt0[rr], 1);
        if (p < CAP0) bce0[(size_t)rr*CAP0 + p] = make_int2(c, __float_as_int(f0v[i]));
        return;
      }
      i -= nF0;
      if (i < nS1){
        int rr = s1r[i];
        int p = atomicAdd(&cnt_s1[rr], 1);
        if (p < CAP_S1) bce_s1[(size_t)rr*CAP_S1 + p] = make_int2(s1c[i], __float_as_int(s1v[i]));
        return;
      }
      i -= nS1;
      {
        int rr = f1r[i];
        int c  = fid1[f1c[i]];                  // row of H1b
        int p = atomicAdd(&cnt_f1[rr], 1);
        if (p < CAP_F1) bce_f1[(size_t)rr*CAP_F1 + p] = make_int2(c, __float_as_int(f1v[i]));
      }
      return;
    }
    {
      int ci = (sb*5 + (r-1))*256 + t;          // guard PER8
      if (ci >= PER8) return;
      const f32x4* px = (const f32x4*)(x     + (size_t)ci*8);
      const f32x4* ph = (const f32x4*)(hist0 + (size_t)ci*8);
      f32x4 x0 = __builtin_nontemporal_load(px);
      f32x4 x1 = __builtin_nontemporal_load(px+1);
      f32x4 h0 = __builtin_nontemporal_load(ph);
      f32x4 h1 = __builtin_nontemporal_load(ph+1);
      *(uint2*)(TD + (size_t)ci*8)                    = enc_fp8x8(x0 - h0, x1 - h1);
      *(uint2*)(TD + (size_t)NTAB*D + (size_t)ci*8)   = enc_fp8x8(h0, h1);
      return;
    }
  } else {
    int i = (b - MA_NS*6)*256 + t;              // [0, 131072), 4 elems/thread
    const float* src = (i < 65536) ? w0 : w1;
    unsigned short* dst = (i < 65536) ? w0b : w1b;
    int ii = (i < 65536) ? i : i - 65536;
    f32x4 v = *(const f32x4*)(src + (size_t)ii*4);
    ushort4 o;
    o.x = (unsigned short)f2bf(v[0]); o.y = (unsigned short)f2bf(v[1]);
    o.z = (unsigned short)f2bf(v[2]); o.w = (unsigned short)f2bf(v[3]);
    *(ushort4*)(dst + (size_t)ii*4) = o;
  }
}

// ================= SpMM helpers (capacity-bin CSR) =================
__device__ __forceinline__ void acc_bf16(float* a, uint4 p, float v){
  a[0] += v*bf2f(p.x & 0xffffu); a[1] += v*bf2f(p.x >> 16);
  a[2] += v*bf2f(p.y & 0xffffu); a[3] += v*bf2f(p.y >> 16);
  a[4] += v*bf2f(p.z & 0xffffu); a[5] += v*bf2f(p.z >> 16);
  a[6] += v*bf2f(p.w & 0xffffu); a[7] += v*bf2f(p.w >> 16);
}
__device__ __forceinline__ void acc_fp8(float* a, uint2 q, float v){
  f32x2 d0 = __builtin_amdgcn_cvt_pk_f32_fp8(q.x, false);
  f32x2 d1 = __builtin_amdgcn_cvt_pk_f32_fp8(q.x, true);
  f32x2 d2 = __builtin_amdgcn_cvt_pk_f32_fp8(q.y, false);
  f32x2 d3 = __builtin_amdgcn_cvt_pk_f32_fp8(q.y, true);
  a[0] += v*d0[0]; a[1] += v*d0[1]; a[2] += v*d1[0]; a[3] += v*d1[1];
  a[4] += v*d2[0]; a[5] += v*d2[1]; a[6] += v*d3[0]; a[7] += v*d3[1];
}

__device__ __forceinline__ void spmm_run_bf16(
    const int2* __restrict__ be, int je,
    const unsigned short* __restrict__ H, int lane, float* a)
{
  int j = 0;
  for (; j + 8 <= je; j += 8){
    int2 e[8]; uint4 p[8];
    #pragma unroll
    for (int u=0;u<8;u++) e[u] = be[j+u];
    #pragma unroll
    for (int u=0;u<8;u++) p[u] = *(const uint4*)(H + (size_t)e[u].x*D + lane*8);
    #pragma unroll
    for (int u=0;u<8;u++) acc_bf16(a, p[u], __int_as_float(e[u].y));
  }
  if (j + 4 <= je){
    int2 e[4]; uint4 p[4];
    #pragma unroll
    for (int u=0;u<4;u++) e[u] = be[j+u];
    #pragma unroll
    for (int u=0;u<4;u++) p[u] = *(const uint4*)(H + (size_t)e[u].x*D + lane*8);
    #pragma unroll
    for (int u=0;u<4;u++) acc_bf16(a, p[u], __int_as_float(e[u].y));
    j += 4;
  }
  for (; j < je; j++){
    int2 e = be[j];
    uint4 p = *(const uint4*)(H + (size_t)e.x*D + lane*8);
    acc_bf16(a, p, __int_as_float(e.y));
  }
}

__device__ __forceinline__ void spmm_run_q8(
    const int2* __restrict__ be, int je,
    const unsigned char* __restrict__ Q, int lane, float* a)
{
  int j = 0;
  for (; j + 8 <= je; j += 8){
    int2 e[8]; uint2 q[8];
    #pragma unroll
    for (int u=0;u<8;u++) e[u] = be[j+u];
    #pragma unroll
    for (int u=0;u<8;u++) q[u] = *(const uint2*)(Q + (size_t)e[u].x*D + lane*8);
    #pragma unroll
    for (int u=0;u<8;u++) acc_fp8(a, q[u], __int_as_float(e[u].y));
  }
  if (j + 4 <= je){
    int2 e[4]; uint2 q[4];
    #pragma unroll
    for (int u=0;u<4;u++) e[u] = be[j+u];
    #pragma unroll
    for (int u=0;u<4;u++) q[u] = *(const uint2*)(Q + (size_t)e[u].x*D + lane*8);
    #pragma unroll
    for (int u=0;u<4;u++) acc_fp8(a, q[u], __int_as_float(e[u].y));
    j += 4;
  }
  for (; j < je; j++){
    int2 e = be[j];
    uint2 q = *(const uint2*)(Q + (size_t)e.x*D + lane*8);
    acc_fp8(a, q, __int_as_float(e.y));
  }
}

__device__ __forceinline__ void store_row(unsigned short* out, int row, int lane, const float* a){
  uint4 o;
  o.x = f2bf(a[0]) | (f2bf(a[1]) << 16);
  o.y = f2bf(a[2]) | (f2bf(a[3]) << 16);
  o.z = f2bf(a[4]) | (f2bf(a[5]) << 16);
  o.w = f2bf(a[6]) | (f2bf(a[7]) << 16);
  *(uint4*)(out + (size_t)row*D + lane*8) = o;
}

// ===== SpMMX: spmm0 over [Dq|H0q] (5/7) || hist1->H1b bf16 (2/7) =====
#define SX_NS   1639
#define SX_GRID (SX_NS*7)
#define CONV_BLKS 3125             // 3125*256*8 = 6.4M units

__global__ __launch_bounds__(256) void k_spmmX(
    const int* __restrict__ cnt0, const int2* __restrict__ bce0,
    const unsigned char* __restrict__ TD,
    unsigned short* __restrict__ out, int nrows,
    const float* __restrict__ hist1, unsigned short* __restrict__ H1b)
{
  int b = blockIdx.x, t = threadIdx.x;
  int sb = b / 7, r = b % 7;
  if (r < 5){
    int wid = t >> 6, lane = t & 63;
    int row = (sb*5 + r)*4 + wid;
    if (row >= nrows) return;
    float a[8] = {0.f,0.f,0.f,0.f,0.f,0.f,0.f,0.f};
    int je = min(cnt0[row], CAP0);
    spmm_run_q8(bce0 + (size_t)row*CAP0, je, TD, lane, a);
    store_row(out, row, lane, a);
  } else {
    int cb = sb*2 + (r-5);
    if (cb >= CONV_BLKS) return;
    #pragma unroll
    for (int k=0; k<8; k++){
      int ci = cb*256 + t + k*(CONV_BLKS*256);
      const f32x4* p = (const f32x4*)(hist1 + (size_t)ci*8);
      f32x4 v0 = __builtin_nontemporal_load(p);
      f32x4 v1 = __builtin_nontemporal_load(p+1);
      uint4 o;
      o.x = f2bf(v0[0]) | (f2bf(v0[1])<<16);
      o.y = f2bf(v0[2]) | (f2bf(v0[3])<<16);
      o.z = f2bf(v1[0]) | (f2bf(v1[1])<<16);
      o.w = f2bf(v1[2]) | (f2bf(v1[3])<<16);
      *(uint4*)(H1b + (size_t)ci*8) = o;
    }
  }
}

__global__ __launch_bounds__(256) void k_spmm_acc(
    const int* __restrict__ cnt, const int2* __restrict__ bce, const unsigned short* __restrict__ H,
    unsigned short* __restrict__ out, int nrows)
{
  int wid = threadIdx.x >> 6, lane = threadIdx.x & 63;
  int row = blockIdx.x*4 + wid;
  if (row >= nrows) return;
  float a[8];
  uint4 p = *(const uint4*)(out + (size_t)row*D + lane*8);
  a[0]=bf2f(p.x&0xffffu); a[1]=bf2f(p.x>>16); a[2]=bf2f(p.y&0xffffu); a[3]=bf2f(p.y>>16);
  a[4]=bf2f(p.z&0xffffu); a[5]=bf2f(p.z>>16); a[6]=bf2f(p.w&0xffffu); a[7]=bf2f(p.w>>16);
  int je = min(cnt[row], CAP_S1);
  spmm_run_bf16(bce + (size_t)row*CAP_S1, je, H, lane, a);
  store_row(out, row, lane, a);
}

// ================= GEMM =================
__device__ __forceinline__ void gload16(const unsigned short* g, unsigned short* l){
  __builtin_amdgcn_global_load_lds(
      (const __attribute__((address_space(1))) unsigned int*)(const void*)g,
      (__attribute__((address_space(3))) unsigned int*)(void*)l,
      16, 0, 0);
}

template<bool OUT_BF16>
__device__ __forceinline__ void gemm_block(
    const unsigned short* __restrict__ A,
    const unsigned short* __restrict__ B,
    const float* __restrict__ bias,
    void* __restrict__ Cv,
    int gemm_bid, unsigned short* Al, unsigned short* Bl)
{
  int bx = gemm_bid & 3, by = gemm_bid >> 2;
  int m0 = by << 7, n0 = bx << 7;
  int t = threadIdx.x, wave = t >> 6, lane = t & 63;
  int wr = wave >> 1, wc = wave & 1;
  f32x4 acc[4][4] = {};
  int flat = t << 3;
  int r0 = flat >> 5, cc = flat & 31;
  const unsigned short* pa = A + (size_t)(m0 + r0)*D + cc;
  const unsigned short* pb = B + (size_t)(n0 + r0)*D + cc;
  for (int k0 = 0; k0 < D; k0 += 32){
    gload16(pa + k0,                 &Al[flat]);
    gload16(pa + (size_t)64*D + k0,  &Al[flat + 2048]);
    gload16(pb + k0,                 &Bl[flat]);
    gload16(pb + (size_t)64*D + k0,  &Bl[flat + 2048]);
    __syncthreads();
    int arow = (wr << 6) | (lane & 15);
    int brow = (wc << 6) | (lane & 15);
    int kg   = (lane >> 4) << 3;
    bf16x8 af[4], bfr[4];
    #pragma unroll
    for (int mi=0; mi<4; mi++) af[mi]  = *(const bf16x8*)&Al[(arow + (mi<<4))*32 + kg];
    #pragma unroll
    for (int ni=0; ni<4; ni++) bfr[ni] = *(const bf16x8*)&Bl[(brow + (ni<<4))*32 + kg];
    #pragma unroll
    for (int mi=0; mi<4; mi++)
      #pragma unroll
      for (int ni=0; ni<4; ni++)
        acc[mi][ni] = __builtin_amdgcn_mfma_f32_16x16x32_bf16(af[mi], bfr[ni], acc[mi][ni], 0, 0, 0);
    __syncthreads();
  }
  int crow = m0 + (wr << 6) + ((lane >> 4) << 2);
  int ccol = n0 + (wc << 6) + (lane & 15);
  #pragma unroll
  for (int mi=0; mi<4; mi++){
    #pragma unroll
    for (int q=0; q<4; q++){
      int row = crow + (mi << 4) + q;
      #pragma unroll
      for (int ni=0; ni<4; ni++){
        float val = acc[mi][ni][q] + bias[ccol + (ni << 4)];
        if (OUT_BF16)
          ((unsigned short*)Cv)[(size_t)row*D + ccol + (ni << 4)] = (unsigned short)f2bf(val);
        else
          ((float*)Cv)[(size_t)row*D + ccol + (ni << 4)] = val;
      }
    }
  }
}

// MegaC: gemm0 (1/3) || spmm1 f-init over H1b bf16 (2/3)
__global__ __launch_bounds__(256) void k_megaC(
    const unsigned short* __restrict__ A, const unsigned short* __restrict__ B,
    const float* __restrict__ bias, unsigned short* __restrict__ y1,
    const int* __restrict__ cnt_f1, const int2* __restrict__ bce_f1,
    const unsigned short* __restrict__ H1b, unsigned short* __restrict__ out2, int n2rows)
{
  __shared__ unsigned short Al[128*32];
  __shared__ unsigned short Bl[128*32];
  int b = blockIdx.x, t = threadIdx.x;
  int sb = b / 3, r = b % 3;
  if (r == 0){
    gemm_block<true>(A, B, bias, (void*)y1, sb, Al, Bl);
  } else {
    int wid = t >> 6, lane = t & 63;
    int row = (sb*2 + (r-1))*4 + wid;
    if (row >= n2rows) return;
    float a[8] = {0.f,0.f,0.f,0.f,0.f,0.f,0.f,0.f};
    int je = min(cnt_f1[row], CAP_F1);
    spmm_run_bf16(bce_f1 + (size_t)row*CAP_F1, je, H1b, lane, a);
    store_row(out2, row, lane, a);
  }
}

template<bool OUT_BF16>
__global__ __launch_bounds__(256) void k_gemm_bias(
    const unsigned short* __restrict__ A,
    const unsigned short* __restrict__ B,
    const float* __restrict__ bias,
    void* __restrict__ Cv,
    int M)
{
  __shared__ unsigned short Al[128*32];
  __shared__ unsigned short Bl[128*32];
  gemm_block<OUT_BF16>(A, B, bias, Cv, blockIdx.x, Al, Bl);
}

// ================= LN + ReLU - bf16 H1b[sid1] =================
__global__ __launch_bounds__(256) void k_ln_relu_sub(
    const unsigned short* __restrict__ y, const float* __restrict__ gam, const float* __restrict__ bet,
    const unsigned short* __restrict__ H1b, const int* __restrict__ sid1,
    unsigned short* __restrict__ out)
{
  __shared__ float sh[8];
  int row = blockIdx.x, t = threadIdx.x;
  int c = t << 1;
  unsigned pv = *(const unsigned*)(y + (size_t)row*D + c);
  float vx = bf2f(pv & 0xffffu), vy = bf2f(pv >> 16);
  float s = vx + vy, ss = vx*vx + vy*vy;
  #pragma unroll
  for (int m=1; m<64; m<<=1){ s += __shfl_xor(s, m); ss += __shfl_xor(ss, m); }
  int wave = t >> 6, lane = t & 63;
  if (lane == 0){ sh[wave] = s; sh[4+wave] = ss; }
  __syncthreads();
  s  = sh[0]+sh[1]+sh[2]+sh[3];
  ss = sh[4]+sh[5]+sh[6]+sh[7];
  float mu  = s * (1.f/D);
  float var = ss * (1.f/D) - mu*mu;
  float rr  = rsqrtf(var + 1e-5f);
  int srow = sid1[row];
  unsigned hv = *(const unsigned*)(H1b + (size_t)srow*D + c);
  float o0 = fmaxf((vx - mu)*rr*gam[c]   + bet[c],   0.f) - bf2f(hv & 0xffffu);
  float o1 = fmaxf((vy - mu)*rr*gam[c+1] + bet[c+1], 0.f) - bf2f(hv >> 16);
  *(unsigned*)(out + (size_t)row*D + c) = f2bf(o0) | (f2bf(o1) << 16);
}

// ================= log_softmax =================
__global__ __launch_bounds__(256) void k_logsoftmax(const float* __restrict__ y, float* __restrict__ out){
  __shared__ float sh[8];
  int row = blockIdx.x, t = threadIdx.x;
  int c = t << 1;
  float2 v = *(const float2*)(y + (size_t)row*D + c);
  float m = fmaxf(v.x, v.y);
  #pragma unroll
  for (int k=1; k<64; k<<=1) m = fmaxf(m, __shfl_xor(m, k));
  int wave = t >> 6, lane = t & 63;
  if (lane == 0) sh[wave] = m;
  __syncthreads();
  m = fmaxf(fmaxf(sh[0], sh[1]), fmaxf(sh[2], sh[3]));
  __syncthreads();
  float e = expf(v.x - m) + expf(v.y - m);
  #pragma unroll
  for (int k=1; k<64; k<<=1) e += __shfl_xor(e, k);
  if (lane == 0) sh[4+wave] = e;
  __syncthreads();
  e = sh[4]+sh[5]+sh[6]+sh[7];
  float lse = m + logf(e);
  float2 o; o.x = v.x - lse; o.y = v.y - lse;
  *(float2*)(out + (size_t)row*D + c) = o;
}

extern "C" void kernel_launch(void* const* d_in, const int* in_sizes, int n_in,
                              void* d_out, int out_size, void* d_ws, size_t ws_size,
                              hipStream_t stream)
{
  const float* x     = (const float*)d_in[0];
  const float* hist0 = (const float*)d_in[1];
  const float* hist1 = (const float*)d_in[2];
  const float* w0    = (const float*)d_in[3];
  const float* b0    = (const float*)d_in[4];
  const float* g0    = (const float*)d_in[5];
  const float* beta0 = (const float*)d_in[6];
  const float* w1    = (const float*)d_in[7];
  const float* b1    = (const float*)d_in[8];
  const float* s0v   = (const float*)d_in[9];
  const float* s1v   = (const float*)d_in[10];
  const float* f0v   = (const float*)d_in[11];
  const float* f1v   = (const float*)d_in[12];
  const int* sid0    = (const int*)d_in[13];
  const int* sid1    = (const int*)d_in[14];
  const int* fid0    = (const int*)d_in[16];
  const int* fid1    = (const int*)d_in[17];
  const int* s0r     = (const int*)d_in[18];
  const int* s0c     = (const int*)d_in[19];
  const int* s1r     = (const int*)d_in[20];
  const int* s1c     = (const int*)d_in[21];
  const int* f0r     = (const int*)d_in[22];
  const int* f0c     = (const int*)d_in[23];
  const int* f1r     = (const int*)d_in[24];
  const int* f1c     = (const int*)d_in[25];

  const int N1 = 32768, N2 = 8192;
  const int Es0 = 262144, Es1 = 65536, Ef0 = 1048576, Ef1 = 262144;

  char* ws = (char*)d_ws;
  size_t off = 0;
  auto alloc = [&](size_t bytes)->char*{
    char* p = ws + off; off += (bytes + 255) & ~(size_t)255; return p;
  };
  char* TD_raw = alloc((size_t)2*NTAB*D);         // 102.4MB fp8 [Dq|H0q]; dead after spmmX
  unsigned short* H1b = (unsigned short*)alloc((size_t)NTAB*D*2);  // 102.4MB bf16 hist1
  unsigned short* h1   = (unsigned short*)alloc((size_t)N1*D*2);
  unsigned short* out1 = (unsigned short*)alloc((size_t)N1*D*2);
  unsigned short* w0b  = (unsigned short*)alloc((size_t)D*D*2);
  unsigned short* w1b  = (unsigned short*)alloc((size_t)D*D*2);
  int* cnt0   = (int*)alloc((size_t)N1*4);
  int* cnt_s1 = (int*)alloc((size_t)N2*4);
  int* cnt_f1 = (int*)alloc((size_t)N2*4);
  int2* bce0   = (int2*)alloc((size_t)N1*CAP0*8);     // 33.6MB
  int2* bce_s1 = (int2*)alloc((size_t)N2*CAP_S1*8);   // 3.1MB
  int2* bce_f1 = (int2*)alloc((size_t)N2*CAP_F1*8);   // 6.3MB

  unsigned char*  TD   = (unsigned char*)TD_raw;
  unsigned short* y1   = (unsigned short*)TD_raw;                      // @0 after spmmX
  float*          y2   = (float*)(TD_raw + ((size_t)34<<20));
  unsigned short* out2 = (unsigned short*)(TD_raw + ((size_t)52<<20));
  float*          outp = (float*)d_out;

  hipMemsetAsync(cnt0, 0, (size_t)(N1 + 2*N2)*4, stream);
  // MegaA: fills (capacity bins) || (x-hist0)->Dq + hist0->H0q || weights->bf16
  k_megaA<<<MA_GRID, 256, 0, stream>>>(
      s0r, s0c, s0v, Es0, f0r, f0c, f0v, Ef0,
      s1r, s1c, s1v, Es1, f1r, f1c, f1v, Ef1,
      sid0, fid0, fid1,
      cnt0, bce0, cnt_s1, bce_s1, cnt_f1, bce_f1,
      x, hist0, TD, w0, w1, w0b, w1b);
  // SpMMX: layer-0 merged fp8 SpMM || hist1->H1b
  k_spmmX<<<SX_GRID, 256, 0, stream>>>(cnt0, bce0, TD, out1, N1, hist1, H1b);
  // MegaC: gemm0 (out1@w0 -> y1 bf16) || spmm1 f-init (H1b -> out2)
  k_megaC<<<1024*3, 256, 0, stream>>>(out1, w0b, b0, y1, cnt_f1, bce_f1, H1b, out2, N2);
  // LN + ReLU - bf16 H1b[sid1] -> h1
  k_ln_relu_sub<<<N1, 256, 0, stream>>>(y1, g0, beta0, H1b, sid1, h1);
  // layer-1 s-phase accumulate
  k_spmm_acc<<<N2/4, 256, 0, stream>>>(cnt_s1, bce_s1, h1, out2, N2);
  // dense + log-softmax
  k_gemm_bias<false><<<(N2/128)*4, 256, 0, stream>>>(out2, w1b, b1, (void*)y2, N2);
  k_logsoftmax<<<N2, 256, 0, stream>>>(y2, outp);
}